// Round 6
// baseline (150.211 us; speedup 1.0000x reference)
//
#include <hip/hip_runtime.h>
#include <hip/hip_bf16.h>

#define NFFT    512
#define HOPSZ   128
#define FBINS   257
#define TFR     2048
#define NBC     32            // B*C
#define OUTLEN  262016        // (T-1)*HOP
#define SPAD    256           // n_fft/2 (center trim)

typedef __bf16 bf16x8 __attribute__((ext_vector_type(8)));
typedef float  f32x4  __attribute__((ext_vector_type(4)));

static __device__ __forceinline__ float bf2f(unsigned short u) {
    union { unsigned int i; float f; } x; x.i = (unsigned int)u << 16; return x.f;
}

__device__ __forceinline__ void gld_lds16(const void* g, void* l) {
    __builtin_amdgcn_global_load_lds(
        (const __attribute__((address_space(1))) unsigned int*)g,
        (__attribute__((address_space(3))) unsigned int*)l, 16, 0, 0);
}

// ---------------------------------------------------------------------------
// Kernel 1: W' in MFMA A-fragment order (verified R2-R5).
//   Wf[(ks*32 + rt)*64 + lane]: 8 bf16, elem j:
//     n = rt*16 + (lane&15),  k = ks*32 + 4*(lane>>4) + (j&3) + 16*(j>>2)
// ---------------------------------------------------------------------------
__global__ __launch_bounds__(256) void k_wgen(const float* __restrict__ wnd,
                                              uint4* __restrict__ Wf) {
    const int gid  = blockIdx.x * 256 + threadIdx.x;   // < 34816
    const int lane = gid & 63;
    const int rt   = (gid >> 6) & 31;
    const int ks   = gid >> 11;
    const int n    = rt * 16 + (lane & 15);
    const int kb   = ks * 32 + ((lane >> 4) << 2);
    const float wn = wnd[n] * (1.0f / 512.0f);
    union { uint4 u; unsigned short h[8]; } o;
    #pragma unroll
    for (int j = 0; j < 8; ++j) {
        const int k = kb + (j & 3) + 16 * (j >> 2);
        float val = 0.0f;
        if (k < 2 * FBINS) {
            const int f = k >> 1;
            const bool edge = (f == 0) || (f == 256);
            const float cf = edge ? 1.0f : 2.0f;
            const int m = (f * n) & (NFFT - 1);
            const float ang = (float)m * 0.01227184630308513f; // 2*pi/512
            float s, c;
            __sincosf(ang, &s, &c);
            val = (k & 1) ? (edge ? 0.0f : -cf * wn * s) : (cf * wn * c);
        }
        __hip_bfloat16 hb = __float2bfloat16(val);
        o.h[j] = *(unsigned short*)&hb;
    }
    Wf[gid] = o.u;
}

// ---------------------------------------------------------------------------
// Kernel 2: frames(k<512) = W'[:, :512] @ X — weight-stationary, ONE barrier.
//   512 blocks x 512 thr (8 waves). Block: M-slice 128 rows (m=id&3) x 512 t
//   (tq=(id>>2)&3), bc=id>>4. XCD-chunk: the 4 m-blocks of one (bc,tq) land
//   on the same XCD -> X panel read once from HBM, shared via L2.
//   A-slice (128 rows x 512 K = 128 KB bf16, fragment order) -> LDS once via
//   16 global_load_lds slabs; vmcnt(0)+barrier ONCE; then each wave streams
//   64 t-cols independently: 2 tiles x 16 ks of {8 B-loads (2-deep reg
//   prefetch, compiler-tracked), 8 ds_read_b128 (conflict-free), 16 MFMA}.
//   No barriers, no manual vmcnt in the stream.
// ---------------------------------------------------------------------------
__global__ __launch_bounds__(512, 2) void k_mm(
    const float* __restrict__ X,
    const uint4* __restrict__ Wf,
    __hip_bfloat16* __restrict__ frames)
{
    __shared__ uint4 AbL[8192];     // 128 KB: [ks][mi][lane] (m201 precedent)

    const int tid  = threadIdx.x;
    const int lane = tid & 63;
    const int w    = tid >> 6;

    const int bid = blockIdx.x;                 // 512 blocks, 512 % 8 == 0
    const int id  = (bid & 7) * 64 + (bid >> 3);
    const int m   = id & 3;                     // M-slice: rows [128m, +128)
    const int tq  = (id >> 2) & 3;              // 512-t quarter
    const int bc  = id >> 4;                    // 0..31

    const float2* __restrict__ X2 = (const float2*)X + (size_t)bc * FBINS * TFR;
    const int q   = lane >> 4;
    const int rlo = lane & 15;
    const int t0w = tq * 512 + w * 64;          // this wave's 64 t-cols

    // ---- A-slice -> LDS, once ----
    {
        const uint4* src = Wf + m * 512 + tid;
        #pragma unroll
        for (int ks = 0; ks < 16; ++ks)
            gld_lds16(src + ks * 2048, &AbL[ks * 512 + tid]);
        asm volatile("s_waitcnt vmcnt(0)" ::: "memory");
        __builtin_amdgcn_s_barrier();
    }

    auto loadB = [&](int tbase, int ks, float2 (&bx)[2][4]) {
        const float2* xb = X2 + (size_t)(ks * 16 + 2 * q) * TFR;
        #pragma unroll
        for (int ni = 0; ni < 2; ++ni) {
            const float2* xt = xb + tbase + ni * 16 + rlo;
            bx[ni][0] = xt[0];
            bx[ni][1] = xt[TFR];
            bx[ni][2] = xt[8 * TFR];
            bx[ni][3] = xt[9 * TFR];
        }
    };

    unsigned short* fb = (unsigned short*)frames;

    #pragma unroll
    for (int tt = 0; tt < 2; ++tt) {
        const int tbase = t0w + tt * 32;
        f32x4  acc[8][2] = {};
        float2 bx[3][2][4];

        loadB(tbase, 0, bx[0]);
        loadB(tbase, 1, bx[1]);
        #pragma unroll
        for (int ks = 0; ks < 16; ++ks) {
            if (ks + 2 < 16) loadB(tbase, ks + 2, bx[(ks + 2) % 3]);
            // pack B frags (R2-verified layout)
            uint4 b[2];
            #pragma unroll
            for (int ni = 0; ni < 2; ++ni) {
                union { unsigned short h[8]; uint4 u; } pk;
                #pragma unroll
                for (int d = 0; d < 4; ++d) {
                    __hip_bfloat16 x = __float2bfloat16(bx[ks % 3][ni][d].x);
                    __hip_bfloat16 y = __float2bfloat16(bx[ks % 3][ni][d].y);
                    pk.h[2 * d]     = *(unsigned short*)&x;
                    pk.h[2 * d + 1] = *(unsigned short*)&y;
                }
                b[ni] = pk.u;
            }
            uint4 a[8];
            const uint4* Ap = &AbL[ks * 512 + lane];
            #pragma unroll
            for (int mi = 0; mi < 8; ++mi) a[mi] = Ap[mi * 64];
            #pragma unroll
            for (int mi = 0; mi < 8; ++mi)
                #pragma unroll
                for (int ni = 0; ni < 2; ++ni)
                    acc[mi][ni] = __builtin_amdgcn_mfma_f32_16x16x32_bf16(
                        __builtin_bit_cast(bf16x8, a[mi]),
                        __builtin_bit_cast(bf16x8, b[ni]), acc[mi][ni], 0, 0, 0);
        }
        // epilogue: C/D row=(l>>4)*4+reg -> n, col=l&15 -> t (verified R1-R5)
        #pragma unroll
        for (int mi = 0; mi < 8; ++mi) {
            const int nbase = m * 128 + mi * 16 + q * 4;
            #pragma unroll
            for (int ni = 0; ni < 2; ++ni) {
                const int t = tbase + ni * 16 + rlo;
                union { ushort4 u; __hip_bfloat16 hh[4]; } pk;
                pk.hh[0] = __float2bfloat16(acc[mi][ni][0]);
                pk.hh[1] = __float2bfloat16(acc[mi][ni][1]);
                pk.hh[2] = __float2bfloat16(acc[mi][ni][2]);
                pk.hh[3] = __float2bfloat16(acc[mi][ni][3]);
                *(ushort4*)(fb + (((size_t)(bc * TFR + t)) << 9) + nbase) = pk.u;
            }
        }
    }
}

// ---------------------------------------------------------------------------
// Kernel 3: overlap-add + envelope normalize + the k=512 DC term (R5-verified).
//   W'[n][512] = wnd[n]*(1/512)*(-1)^n ; contribution = W'[n][512]*re(X[256,t]).
// ---------------------------------------------------------------------------
__global__ __launch_bounds__(256) void k_ola(
    const __hip_bfloat16* __restrict__ frames,
    const float* __restrict__ wnd,
    const float* __restrict__ X,
    float* __restrict__ out)
{
    const int bc = blockIdx.y;
    const int o  = (blockIdx.x * 256 + threadIdx.x) * 4;
    if (o >= OUTLEN) return;
    const int s   = o + SPAD;
    const int tb_ = s >> 7;
    const int nb  = s & (HOPSZ - 1);
    const unsigned short* fb = (const unsigned short*)frames + (size_t)bc * TFR * NFFT;
    const float* Xre = X + (((size_t)bc * FBINS + 256) * TFR) * 2;  // re at [2t]
    const float sA = ((nb & 1) ? -1.0f : 1.0f) * (1.0f / 512.0f);
    float y0 = 0.f, y1 = 0.f, y2 = 0.f, y3 = 0.f;
    float e0 = 0.f, e1 = 0.f, e2 = 0.f, e3 = 0.f;
    #pragma unroll
    for (int r = 0; r < 4; ++r) {
        const int t = tb_ - r;
        if ((unsigned)t > (unsigned)(TFR - 1)) continue;
        const int n = nb + (r << 7);
        ushort4 v = *(const ushort4*)(fb + (size_t)t * NFFT + n);
        float4  wv = *(const float4*)(wnd + n);
        const float c = sA * Xre[2 * t];
        y0 += bf2f(v.x) + c * wv.x; e0 += wv.x * wv.x;
        y1 += bf2f(v.y) - c * wv.y; e1 += wv.y * wv.y;
        y2 += bf2f(v.z) + c * wv.z; e2 += wv.z * wv.z;
        y3 += bf2f(v.w) - c * wv.w; e3 += wv.w * wv.w;
    }
    float4 res = make_float4(y0 / e0, y1 / e1, y2 / e2, y3 / e3);
    *(float4*)(out + (size_t)bc * OUTLEN + o) = res;
}

// ---------------------------------------------------------------------------
extern "C" void kernel_launch(void* const* d_in, const int* in_sizes, int n_in,
                              void* d_out, int out_size, void* d_ws, size_t ws_size,
                              hipStream_t stream) {
    (void)in_sizes; (void)n_in; (void)out_size; (void)ws_size;
    const float* X   = (const float*)d_in[0];
    const float* wnd = (const float*)d_in[1];
    float* out = (float*)d_out;

    uint4* Wf = (uint4*)d_ws;                                            // 544 KB
    __hip_bfloat16* frames = (__hip_bfloat16*)((char*)d_ws + (1 << 20)); // 64 MB

    k_wgen<<<136, 256, 0, stream>>>(wnd, Wf);
    k_mm<<<512, 512, 0, stream>>>(X, Wf, frames);
    k_ola<<<dim3((OUTLEN / 4 + 255) / 256, NBC), 256, 0, stream>>>(frames, wnd, X, out);
}

// Round 7
// 84.216 us; speedup vs baseline: 1.7837x; 1.7837x over previous
//
#include <hip/hip_runtime.h>
#include <hip/hip_bf16.h>

#define NFFT    512
#define HOPSZ   128
#define FBINS   257
#define TFR     2048
#define NBC     32            // B*C
#define OUTLEN  262016        // (T-1)*HOP
#define SPAD    256           // n_fft/2 (center trim)

typedef __bf16 bf16x8 __attribute__((ext_vector_type(8)));
typedef float  f32x4  __attribute__((ext_vector_type(4)));

static __device__ __forceinline__ float bf2f(unsigned short u) {
    union { unsigned int i; float f; } x; x.i = (unsigned int)u << 16; return x.f;
}

__device__ __forceinline__ void gld_lds16(const void* g, void* l) {
    __builtin_amdgcn_global_load_lds(
        (const __attribute__((address_space(1))) unsigned int*)g,
        (__attribute__((address_space(3))) unsigned int*)l, 16, 0, 0);
}

// ---------------------------------------------------------------------------
// Kernel 1: W' in MFMA A-fragment order (verified R2-R6).
//   Wf[(ksw*32 + rt)*64 + lane]: 8 bf16, elem j:
//     n = rt*16 + (lane&15),  k = ksw*32 + 4*(lane>>4) + (j&3) + 16*(j>>2)
// ---------------------------------------------------------------------------
__global__ __launch_bounds__(256) void k_wgen(const float* __restrict__ wnd,
                                              uint4* __restrict__ Wf) {
    const int gid  = blockIdx.x * 256 + threadIdx.x;   // < 34816
    const int lane = gid & 63;
    const int rt   = (gid >> 6) & 31;
    const int ks   = gid >> 11;
    const int n    = rt * 16 + (lane & 15);
    const int kb   = ks * 32 + ((lane >> 4) << 2);
    const float wn = wnd[n] * (1.0f / 512.0f);
    union { uint4 u; unsigned short h[8]; } o;
    #pragma unroll
    for (int j = 0; j < 8; ++j) {
        const int k = kb + (j & 3) + 16 * (j >> 2);
        float val = 0.0f;
        if (k < 2 * FBINS) {
            const int f = k >> 1;
            const bool edge = (f == 0) || (f == 256);
            const float cf = edge ? 1.0f : 2.0f;
            const int m = (f * n) & (NFFT - 1);
            const float ang = (float)m * 0.01227184630308513f; // 2*pi/512
            float s, c;
            __sincosf(ang, &s, &c);
            val = (k & 1) ? (edge ? 0.0f : -cf * wn * s) : (cf * wn * c);
        }
        __hip_bfloat16 hb = __float2bfloat16(val);
        o.h[j] = *(unsigned short*)&hb;
    }
    Wf[gid] = o.u;
}

// ---------------------------------------------------------------------------
// Kernel 2: frames(k<512) = W'[:, :512] @ X.  R1 macro-shape: BM=512 (X read
//   ONCE chip-wide), BT=64, BK=64 -> 8 barrier periods (vs R1's 17).
//   1024 blocks x 512 thr; wave w: rows [64w,+64) x all 64 t; acc[4][4].
//   A: fragment-ordered Wf -> LDS via global_load_lds (linear dest, 0-conflict,
//      no VGPR roundtrip). B: X float2 loads (issued BEFORE A's DMA) -> bf16
//      pack -> LDS [kk][q][t] uint4 (b128 reads uniform 2-way = free).
//   2 __syncthreads per period (compiler-managed waits; no manual vmcnt).
// ---------------------------------------------------------------------------
__global__ __launch_bounds__(512, 4) void k_mm(
    const float* __restrict__ X,
    const uint4* __restrict__ Wf,
    __hip_bfloat16* __restrict__ frames)
{
    __shared__ uint4 Ab[2][32][64];   // [kk][rt][lane] 64 KB
    __shared__ uint4 Bb[2][4][64];    // [kk][q][t]      8 KB

    const int tid  = threadIdx.x;
    const int lane = tid & 63;
    const int w    = tid >> 6;        // wave -> rows [64w, +64)
    const int q    = lane >> 4;
    const int rlo  = lane & 15;

    const int bid = blockIdx.x;       // 1024 = 8 XCD-chunks of 128
    const int id  = (bid & 7) * 128 + (bid >> 3);
    const int bc  = id >> 5;          // 0..31
    const int t0b = (id & 31) << 6;   // 64-t panel

    const float2* __restrict__ X2 = (const float2*)X + (size_t)bc * FBINS * TFR;

    // B staging role: sf = f_local 0..31, st = t base 0..15 (t = st + 16d)
    const int sf  = tid >> 4;
    const int st  = tid & 15;
    const int r2  = (2 * sf) & 31;
    const int skk = sf >> 4;
    const int sq  = (r2 & 15) >> 2;
    const int sj  = ((r2 & 2) >> 1) + (((r2 >> 4) & 1) << 1);
    unsigned int* __restrict__ BbU = (unsigned int*)Bb;

    f32x4 acc[4][4] = {};

    for (int ks = 0; ks < 8; ++ks) {
        __syncthreads();                       // previous compute done
        // --- B loads FIRST (so B ds_writes don't wait on A's DMA) ---
        float2 xv[4];
        const float2* xb = X2 + (size_t)(ks * 32 + sf) * TFR + t0b + st;
        #pragma unroll
        for (int d = 0; d < 4; ++d) xv[d] = xb[16 * d];
        // --- A: 8x global_load_lds dwordx4 (2 slabs of 32 KB) ---
        #pragma unroll
        for (int s = 0; s < 2; ++s) {
            const uint4* src = Wf + (size_t)(2 * ks + s) * 2048;
            uint4* dst = &Ab[s][0][0];
            #pragma unroll
            for (int r = 0; r < 4; ++r)
                gld_lds16(src + r * 512 + tid, dst + r * 512 + tid);
        }
        // --- B pack + LDS writes (b32, ~2-4 way max) ---
        #pragma unroll
        for (int d = 0; d < 4; ++d) {
            union { unsigned int u; __hip_bfloat16 h[2]; } p;
            p.h[0] = __float2bfloat16(xv[d].x);
            p.h[1] = __float2bfloat16(xv[d].y);
            BbU[(((((skk << 2) + sq) << 6) + st + (d << 4)) << 2) + sj] = p.u;
        }
        __syncthreads();                       // staged (auto vmcnt0/lgkm0)
        // --- compute: 32 MFMA / wave ---
        #pragma unroll
        for (int kk = 0; kk < 2; ++kk) {
            uint4 a[4], b[4];
            #pragma unroll
            for (int ni = 0; ni < 4; ++ni) b[ni] = Bb[kk][q][ni * 16 + rlo];
            #pragma unroll
            for (int mi = 0; mi < 4; ++mi) a[mi] = Ab[kk][4 * w + mi][lane];
            #pragma unroll
            for (int mi = 0; mi < 4; ++mi)
                #pragma unroll
                for (int ni = 0; ni < 4; ++ni)
                    acc[mi][ni] = __builtin_amdgcn_mfma_f32_16x16x32_bf16(
                        __builtin_bit_cast(bf16x8, a[mi]),
                        __builtin_bit_cast(bf16x8, b[ni]), acc[mi][ni], 0, 0, 0);
        }
    }

    // epilogue: C/D row=(l>>4)*4+reg -> n, col=l&15 -> t (verified R1-R6)
    unsigned short* fb = (unsigned short*)frames;
    #pragma unroll
    for (int mi = 0; mi < 4; ++mi) {
        const int nbase = (w << 6) + (mi << 4) + (q << 2);
        #pragma unroll
        for (int ni = 0; ni < 4; ++ni) {
            const int t = t0b + ni * 16 + rlo;
            union { ushort4 u; __hip_bfloat16 hh[4]; } pk;
            pk.hh[0] = __float2bfloat16(acc[mi][ni][0]);
            pk.hh[1] = __float2bfloat16(acc[mi][ni][1]);
            pk.hh[2] = __float2bfloat16(acc[mi][ni][2]);
            pk.hh[3] = __float2bfloat16(acc[mi][ni][3]);
            *(ushort4*)(fb + (((size_t)(bc * TFR + t)) << 9) + nbase) = pk.u;
        }
    }
}

// ---------------------------------------------------------------------------
// Kernel 3: overlap-add + envelope normalize + the k=512 DC term (R5/R6-
//   verified).  W'[n][512] = wnd[n]*(1/512)*(-1)^n; contrib = that * re(X[256,t]).
// ---------------------------------------------------------------------------
__global__ __launch_bounds__(256) void k_ola(
    const __hip_bfloat16* __restrict__ frames,
    const float* __restrict__ wnd,
    const float* __restrict__ X,
    float* __restrict__ out)
{
    const int bc = blockIdx.y;
    const int o  = (blockIdx.x * 256 + threadIdx.x) * 4;
    if (o >= OUTLEN) return;
    const int s   = o + SPAD;
    const int tb_ = s >> 7;
    const int nb  = s & (HOPSZ - 1);
    const unsigned short* fb = (const unsigned short*)frames + (size_t)bc * TFR * NFFT;
    const float* Xre = X + (((size_t)bc * FBINS + 256) * TFR) * 2;  // re at [2t]
    const float sA = ((nb & 1) ? -1.0f : 1.0f) * (1.0f / 512.0f);
    float y0 = 0.f, y1 = 0.f, y2 = 0.f, y3 = 0.f;
    float e0 = 0.f, e1 = 0.f, e2 = 0.f, e3 = 0.f;
    #pragma unroll
    for (int r = 0; r < 4; ++r) {
        const int t = tb_ - r;
        if ((unsigned)t > (unsigned)(TFR - 1)) continue;
        const int n = nb + (r << 7);
        ushort4 v = *(const ushort4*)(fb + (size_t)t * NFFT + n);
        float4  wv = *(const float4*)(wnd + n);
        const float c = sA * Xre[2 * t];
        y0 += bf2f(v.x) + c * wv.x; e0 += wv.x * wv.x;
        y1 += bf2f(v.y) - c * wv.y; e1 += wv.y * wv.y;
        y2 += bf2f(v.z) + c * wv.z; e2 += wv.z * wv.z;
        y3 += bf2f(v.w) - c * wv.w; e3 += wv.w * wv.w;
    }
    float4 res = make_float4(y0 / e0, y1 / e1, y2 / e2, y3 / e3);
    *(float4*)(out + (size_t)bc * OUTLEN + o) = res;
}

// ---------------------------------------------------------------------------
extern "C" void kernel_launch(void* const* d_in, const int* in_sizes, int n_in,
                              void* d_out, int out_size, void* d_ws, size_t ws_size,
                              hipStream_t stream) {
    (void)in_sizes; (void)n_in; (void)out_size; (void)ws_size;
    const float* X   = (const float*)d_in[0];
    const float* wnd = (const float*)d_in[1];
    float* out = (float*)d_out;

    uint4* Wf = (uint4*)d_ws;                                            // 544 KB
    __hip_bfloat16* frames = (__hip_bfloat16*)((char*)d_ws + (1 << 20)); // 64 MB

    k_wgen<<<136, 256, 0, stream>>>(wnd, Wf);
    k_mm<<<1024, 512, 0, stream>>>(X, Wf, frames);
    k_ola<<<dim3((OUTLEN / 4 + 255) / 256, NBC), 256, 0, stream>>>(frames, wnd, X, out);
}